// Round 1
// baseline (764.405 us; speedup 1.0000x reference)
//
#include <hip/hip_runtime.h>

using f32x4 = __attribute__((ext_vector_type(4))) float;
using bf16x8 = __attribute__((ext_vector_type(8))) short;

#define DEVI __device__ __forceinline__

// fp32 -> bf16 (RTNE, no NaN handling needed: all values finite)
DEVI short f2bf(float f) {
    unsigned int u = __float_as_uint(f);
    unsigned int r = (u + 0x7fffu + ((u >> 16) & 1u)) >> 16;
    return (short)r;
}

constexpr int NB = 8192;   // windows
constexpr int NT = 49;     // tokens per window
constexpr int CD = 128;    // channels
constexpr int NH = 4;      // heads
constexpr float SCALE = 0.17677669529663687f; // 32^-0.5
constexpr float LOG2E = 1.4426950408889634f;

// ws layout (bytes)
constexpr size_t WS_QKVWT  = 0;       // 384*128 bf16 = 98304 B  (qkv_w transposed, N-major)
constexpr size_t WS_PROJWT = 98304;   // 128*128 bf16 = 32768 B  (proj_w transposed)
constexpr size_t WS_BIAS   = 131072;  // 4*2401 f32   = 38416 B  (gathered rel bias [h][q][k])

__global__ __launch_bounds__(256) void prep_kernel(
    const float* __restrict__ qkv_w, const float* __restrict__ proj_w,
    const float* __restrict__ rbt, const int* __restrict__ rel_index,
    short* __restrict__ qkvwT, short* __restrict__ projwT, float* __restrict__ biasT)
{
    int i = blockIdx.x * 256 + threadIdx.x;
    if (i < 384 * 128) { int j = i >> 7, k = i & 127; qkvwT[i] = f2bf(qkv_w[k * 384 + j]); }
    if (i < 128 * 128) { int j = i >> 7, k = i & 127; projwT[i] = f2bf(proj_w[k * 128 + j]); }
    if (i < NH * NT * NT) { int h = i / (NT * NT); int t = i % (NT * NT); biasT[i] = rbt[rel_index[t] * NH + h]; }
}

__global__ __launch_bounds__(256) void winattn_kernel(
    const float* __restrict__ x, const float* __restrict__ mask,
    const float* __restrict__ qkv_b, const float* __restrict__ proj_b,
    const short* __restrict__ qkvwT, const short* __restrict__ projwT,
    const float* __restrict__ biasT, float* __restrict__ out)
{
    // 64 KB LDS pool (shorts). Phase-aliased:
    //  [0,16384)      qk: [h][2][64][32]  (q at +0, k at +2048 per head); later P: per-head [64][64]
    //  [16384,24576)  vT: [h][32][64]     (v transposed: [d][token])
    //  [24576,32768)  xs: [64][128] bf16 x; later o: [64][128]
    __shared__ short pool[32768];
    short* qk = pool;
    short* vT = pool + 16384;
    short* xs = pool + 24576;

    const int b = blockIdx.x;
    const int tid = threadIdx.x;
    const int wave = tid >> 6;
    const int lane = tid & 63;
    const int lr = lane & 15;   // fragment col/row lane index
    const int lg = lane >> 4;   // fragment k-group

    // ---- stage x -> xs (bf16), zero-pad rows 49..63 ----
    {
        const float4* xb = reinterpret_cast<const float4*>(x + (long)b * NT * CD);
        for (int i4 = tid; i4 < 64 * 32; i4 += 256) {
            int row = i4 >> 5;
            float4 v;
            if (row < NT) v = xb[i4];
            else { v.x = 0.f; v.y = 0.f; v.z = 0.f; v.w = 0.f; }
            short4 s4;
            s4.x = f2bf(v.x); s4.y = f2bf(v.y); s4.z = f2bf(v.z); s4.w = f2bf(v.w);
            *reinterpret_cast<short4*>(&xs[i4 * 4]) = s4;
        }
    }
    __syncthreads();

    // ---- QKV GEMM: wave w owns rows [16w,16w+16), all 384 cols, K=128 ----
    {
        bf16x8 a[4];
#pragma unroll
        for (int kt = 0; kt < 4; ++kt)
            a[kt] = *reinterpret_cast<const bf16x8*>(&xs[(16 * wave + lr) * 128 + kt * 32 + lg * 8]);

#pragma unroll
        for (int nt = 0; nt < 24; ++nt) {
            f32x4 acc = {0.f, 0.f, 0.f, 0.f};
#pragma unroll
            for (int kt = 0; kt < 4; ++kt) {
                bf16x8 bb = *reinterpret_cast<const bf16x8*>(&qkvwT[(nt * 16 + lr) * 128 + kt * 32 + lg * 8]);
                acc = __builtin_amdgcn_mfma_f32_16x16x32_bf16(a[kt], bb, acc, 0, 0, 0);
            }
            int j = nt * 16 + lr;       // global qkv col
            int s = j >> 7;             // 0=q 1=k 2=v (uniform per nt)
            int rem = j & 127;
            int h = rem >> 5;           // head (uniform per nt)
            int d = rem & 31;
            float bias = qkv_b[j];
#pragma unroll
            for (int r = 0; r < 4; ++r) {
                int row = 16 * wave + lg * 4 + r;
                float v = acc[r] + bias;
                if (s == 0)      qk[h * 4096 + row * 32 + d] = f2bf(v * SCALE);
                else if (s == 1) qk[h * 4096 + 2048 + row * 32 + d] = f2bf(v);
                else             vT[h * 2048 + d * 64 + row] = f2bf(v);
            }
        }
    }
    __syncthreads();

    // ---- attention: wave = head ----
    {
        const int h = wave;
        const short* qh = qk + h * 4096;
        const short* kh = qk + h * 4096 + 2048;
        bf16x8 qa[4], kb[4];
#pragma unroll
        for (int t = 0; t < 4; ++t) {
            qa[t] = *reinterpret_cast<const bf16x8*>(&qh[(16 * t + lr) * 32 + lg * 8]);
            kb[t] = *reinterpret_cast<const bf16x8*>(&kh[(16 * t + lr) * 32 + lg * 8]);
        }
        f32x4 sacc[4][4];
#pragma unroll
        for (int mt = 0; mt < 4; ++mt)
#pragma unroll
            for (int ct = 0; ct < 4; ++ct) {
                f32x4 z = {0.f, 0.f, 0.f, 0.f};
                sacc[mt][ct] = __builtin_amdgcn_mfma_f32_16x16x32_bf16(qa[mt], kb[ct], z, 0, 0, 0);
            }

        short* Pl = qk + h * 4096;  // [64][64] bf16, overwrites dead q/k of this head
        const float* maskb = mask + (long)b * NT * NT;
        const float* biash = biasT + h * NT * NT;

#pragma unroll
        for (int mt = 0; mt < 4; ++mt) {
#pragma unroll
            for (int r = 0; r < 4; ++r) {
                int R = 16 * mt + lg * 4 + r;   // query row
                float vals[4];
#pragma unroll
                for (int ct = 0; ct < 4; ++ct) {
                    int c = 16 * ct + lr;       // key col
                    float sv = sacc[mt][ct][r];
                    if (c < NT) {
                        if (R < NT) sv += biash[R * NT + c] + maskb[R * NT + c];
                    } else {
                        sv = -1e30f;
                    }
                    vals[ct] = sv;
                }
                float m = fmaxf(fmaxf(vals[0], vals[1]), fmaxf(vals[2], vals[3]));
                m = fmaxf(m, __shfl_xor(m, 1));
                m = fmaxf(m, __shfl_xor(m, 2));
                m = fmaxf(m, __shfl_xor(m, 4));
                m = fmaxf(m, __shfl_xor(m, 8));
                float sum = 0.f;
#pragma unroll
                for (int ct = 0; ct < 4; ++ct) {
                    float e = exp2f((vals[ct] - m) * LOG2E);
                    vals[ct] = e;
                    sum += e;
                }
                sum += __shfl_xor(sum, 1);
                sum += __shfl_xor(sum, 2);
                sum += __shfl_xor(sum, 4);
                sum += __shfl_xor(sum, 8);
                float inv = 1.0f / sum;
#pragma unroll
                for (int ct = 0; ct < 4; ++ct)
                    Pl[R * 64 + 16 * ct + lr] = f2bf(vals[ct] * inv);
            }
        }

        // ---- P @ V -> o ----
        f32x4 oacc[4][2];
#pragma unroll
        for (int mt = 0; mt < 4; ++mt)
#pragma unroll
            for (int nt = 0; nt < 2; ++nt)
                oacc[mt][nt] = f32x4{0.f, 0.f, 0.f, 0.f};

#pragma unroll
        for (int mt = 0; mt < 4; ++mt) {
            bf16x8 pa[2];
            pa[0] = *reinterpret_cast<const bf16x8*>(&Pl[(16 * mt + lr) * 64 + lg * 8]);
            pa[1] = *reinterpret_cast<const bf16x8*>(&Pl[(16 * mt + lr) * 64 + 32 + lg * 8]);
#pragma unroll
            for (int nt = 0; nt < 2; ++nt) {
#pragma unroll
                for (int ks = 0; ks < 2; ++ks) {
                    bf16x8 vb = *reinterpret_cast<const bf16x8*>(&vT[h * 2048 + (16 * nt + lr) * 64 + ks * 32 + lg * 8]);
                    oacc[mt][nt] = __builtin_amdgcn_mfma_f32_16x16x32_bf16(pa[ks], vb, oacc[mt][nt], 0, 0, 0);
                }
            }
        }
        // write o into xs region as [64][128] (x is dead)
        short* o = xs;
#pragma unroll
        for (int mt = 0; mt < 4; ++mt)
#pragma unroll
            for (int nt = 0; nt < 2; ++nt)
#pragma unroll
                for (int r = 0; r < 4; ++r) {
                    int row = 16 * mt + lg * 4 + r;
                    int col = h * 32 + 16 * nt + lr;
                    o[row * 128 + col] = f2bf(oacc[mt][nt][r]);
                }
    }
    __syncthreads();

    // ---- proj: wave w owns rows [16w,16w+16), 128 cols, K=128 ----
    {
        const short* o = xs;
        bf16x8 ao[4];
#pragma unroll
        for (int kt = 0; kt < 4; ++kt)
            ao[kt] = *reinterpret_cast<const bf16x8*>(&o[(16 * wave + lr) * 128 + kt * 32 + lg * 8]);
#pragma unroll
        for (int nt = 0; nt < 8; ++nt) {
            f32x4 acc = {0.f, 0.f, 0.f, 0.f};
#pragma unroll
            for (int kt = 0; kt < 4; ++kt) {
                bf16x8 bb = *reinterpret_cast<const bf16x8*>(&projwT[(nt * 16 + lr) * 128 + kt * 32 + lg * 8]);
                acc = __builtin_amdgcn_mfma_f32_16x16x32_bf16(ao[kt], bb, acc, 0, 0, 0);
            }
            int col = nt * 16 + lr;
            float pb = proj_b[col];
#pragma unroll
            for (int r = 0; r < 4; ++r) {
                int row = 16 * wave + lg * 4 + r;
                if (row < NT)
                    out[((long)b * NT + row) * CD + col] = acc[r] + pb;
            }
        }
    }
}

extern "C" void kernel_launch(void* const* d_in, const int* in_sizes, int n_in,
                              void* d_out, int out_size, void* d_ws, size_t ws_size,
                              hipStream_t stream) {
    const float* x      = (const float*)d_in[0];
    const float* mask   = (const float*)d_in[1];
    const float* qkv_w  = (const float*)d_in[2];
    const float* qkv_b  = (const float*)d_in[3];
    const float* rbt    = (const float*)d_in[4];
    const float* proj_w = (const float*)d_in[5];
    const float* proj_b = (const float*)d_in[6];
    const int*   ridx   = (const int*)d_in[7];
    float* out = (float*)d_out;

    char* ws = (char*)d_ws;
    short* qkvwT  = (short*)(ws + WS_QKVWT);
    short* projwT = (short*)(ws + WS_PROJWT);
    float* biasT  = (float*)(ws + WS_BIAS);

    prep_kernel<<<192, 256, 0, stream>>>(qkv_w, proj_w, rbt, ridx, qkvwT, projwT, biasT);
    winattn_kernel<<<NB, 256, 0, stream>>>(x, mask, qkv_b, proj_b, qkvwT, projwT, biasT, out);
}

// Round 2
// 597.777 us; speedup vs baseline: 1.2787x; 1.2787x over previous
//
#include <hip/hip_runtime.h>

using f32x4 = __attribute__((ext_vector_type(4))) float;
using bf16x8 = __attribute__((ext_vector_type(8))) short;

#define DEVI __device__ __forceinline__

// fp32 -> bf16 (RTNE; all values finite here)
DEVI short f2bf(float f) {
    unsigned int u = __float_as_uint(f);
    unsigned int r = (u + 0x7fffu + ((u >> 16) & 1u)) >> 16;
    return (short)r;
}
DEVI float bf2f(unsigned short s) {
    unsigned int u = ((unsigned int)s) << 16;
    return __uint_as_float(u);
}

constexpr int NB = 8192;   // windows
constexpr int NT = 49;     // tokens per window
constexpr int CD = 128;    // channels
constexpr int NH = 4;      // heads
constexpr float SCALE = 0.17677669529663687f; // 32^-0.5
constexpr float LOG2E = 1.4426950408889634f;

// LDS pool (shorts)
constexpr int QK_STRIDE = 72;                 // per-row shorts in q/k/P region (144 B, 16B-aligned)
constexpr int QK_HEAD   = 64 * QK_STRIDE;     // 4608 shorts per head
constexpr int VT_BASE   = 4 * QK_HEAD;        // 18432
constexpr int POOL_SH   = VT_BASE + 4 * 32 * 64;  // + 8192 = 26624 shorts = 53248 B -> 3 blocks/CU

// ws layout (bytes)
constexpr size_t WS_QKVWT  = 0;       // 384*128 bf16
constexpr size_t WS_PROJWT = 98304;   // 128*128 bf16
constexpr size_t WS_BIAS   = 131072;  // 4*2401 bf16 (gathered rel bias [h][q][k])

__global__ __launch_bounds__(256) void prep_kernel(
    const float* __restrict__ qkv_w, const float* __restrict__ proj_w,
    const float* __restrict__ rbt, const int* __restrict__ rel_index,
    short* __restrict__ qkvwT, short* __restrict__ projwT, unsigned short* __restrict__ biasBf)
{
    int i = blockIdx.x * 256 + threadIdx.x;
    if (i < 384 * 128) { int j = i >> 7, k = i & 127; qkvwT[i] = f2bf(qkv_w[k * 384 + j]); }
    if (i < 128 * 128) { int j = i >> 7, k = i & 127; projwT[i] = f2bf(proj_w[k * 128 + j]); }
    if (i < NH * NT * NT) { int h = i / (NT * NT); int t = i % (NT * NT); biasBf[i] = (unsigned short)f2bf(rbt[rel_index[t] * NH + h]); }
}

// swizzled index into a [64][128] bf16 tile (xs / o region)
DEVI int swz128(int row, int col) { return row * 128 + (col ^ ((row & 7) << 3)); }

__global__ __launch_bounds__(512, 6) void winattn_kernel(
    const float* __restrict__ x, const float* __restrict__ mask,
    const float* __restrict__ qkv_b, const float* __restrict__ proj_b,
    const short* __restrict__ qkvwT, const short* __restrict__ projwT,
    const unsigned short* __restrict__ biasBf, float* __restrict__ out)
{
    __shared__ short pool[POOL_SH];
    short* qk = pool;            // [4 heads][64][72]: q cols 0..31, k cols 32..63; later P [64][64]
    short* vT = pool + VT_BASE;  // [4 heads][32 d][64 tok], XOR-swizzled; aliases xs and o

    const int b = blockIdx.x;
    const int tid = threadIdx.x;
    const int w = tid >> 6;      // wave 0..7
    const int lane = tid & 63;
    const int lr = lane & 15;
    const int lg = lane >> 4;
    const int wr = w >> 1;       // row-tile / head owner
    const int wh = w & 1;        // half-split selector

    // ---- phase 0: stage x -> xs (bf16, swizzled [64][128]) ----
    {
        short* xs = vT;
        const float4* xb = reinterpret_cast<const float4*>(x + (long)b * NT * CD);
        for (int i4 = tid; i4 < 64 * 32; i4 += 512) {
            int row = i4 >> 5;
            int c = (i4 & 31) * 4;
            float4 v;
            if (row < NT) v = xb[i4];
            else { v.x = 0.f; v.y = 0.f; v.z = 0.f; v.w = 0.f; }
            short4 s4;
            s4.x = f2bf(v.x); s4.y = f2bf(v.y); s4.z = f2bf(v.z); s4.w = f2bf(v.w);
            *reinterpret_cast<short4*>(&xs[swz128(row, c)]) = s4;
        }
    }
    __syncthreads();

    // ---- phase 1: load a-frags (rows 16*wr..+16), then free xs ----
    bf16x8 a[4];
    {
        const short* xs = vT;
#pragma unroll
        for (int kt = 0; kt < 4; ++kt)
            a[kt] = *reinterpret_cast<const bf16x8*>(&xs[swz128(16 * wr + lr, kt * 32 + lg * 8)]);
    }
    __syncthreads();

    // ---- phase 2: QKV GEMM, wave handles rows 16*wr..+16, nt half ----
    {
        int nt0 = wh * 12;
#pragma unroll
        for (int i = 0; i < 12; ++i) {
            int nt = nt0 + i;
            f32x4 acc = {0.f, 0.f, 0.f, 0.f};
#pragma unroll
            for (int kt = 0; kt < 4; ++kt) {
                bf16x8 bb = *reinterpret_cast<const bf16x8*>(&qkvwT[(nt * 16 + lr) * 128 + kt * 32 + lg * 8]);
                acc = __builtin_amdgcn_mfma_f32_16x16x32_bf16(a[kt], bb, acc, 0, 0, 0);
            }
            int s = nt >> 3;            // 0=q 1=k 2=v (uniform per nt)
            int h = (nt >> 1) & 3;      // head (uniform per nt)
            int d = (nt & 1) * 16 + lr; // head dim
            float bias = qkv_b[nt * 16 + lr];
#pragma unroll
            for (int r = 0; r < 4; ++r) {
                int row = 16 * wr + 4 * lg + r;
                float vv = acc[r] + bias;
                if (s == 0)      qk[h * QK_HEAD + row * QK_STRIDE + d] = f2bf(vv * SCALE);
                else if (s == 1) qk[h * QK_HEAD + row * QK_STRIDE + 32 + d] = f2bf(vv);
                else             vT[h * 2048 + d * 64 + (row ^ ((d & 7) << 3))] = f2bf(vv);
            }
        }
    }
    __syncthreads();

    // ---- phase 3: attention. wave -> head wr, query tiles mt0..mt0+1 ----
    {
        const int h = wr;
        const int mt0 = wh * 2;
        short* qh = qk + h * QK_HEAD;

        bf16x8 qa[2], kb[4];
#pragma unroll
        for (int t = 0; t < 2; ++t)
            qa[t] = *reinterpret_cast<const bf16x8*>(&qh[(16 * (mt0 + t) + lr) * QK_STRIDE + lg * 8]);
#pragma unroll
        for (int t = 0; t < 4; ++t)
            kb[t] = *reinterpret_cast<const bf16x8*>(&qh[(16 * t + lr) * QK_STRIDE + 32 + lg * 8]);

        f32x4 sacc[2][4];
#pragma unroll
        for (int mt2 = 0; mt2 < 2; ++mt2)
#pragma unroll
            for (int ct = 0; ct < 4; ++ct) {
                f32x4 z = {0.f, 0.f, 0.f, 0.f};
                sacc[mt2][ct] = __builtin_amdgcn_mfma_f32_16x16x32_bf16(qa[mt2], kb[ct], z, 0, 0, 0);
            }
        __syncthreads();   // all waves' q/k frag loads done before P overwrites

        const float* maskb = mask + (long)b * NT * NT;
        const unsigned short* biash = biasBf + h * NT * NT;

#pragma unroll
        for (int mt2 = 0; mt2 < 2; ++mt2) {
            int mt = mt0 + mt2;
#pragma unroll
            for (int r = 0; r < 4; ++r) {
                int R = 16 * mt + 4 * lg + r;
                bool rv = R < NT;
                float vals[4];
#pragma unroll
                for (int ct = 0; ct < 4; ++ct) {
                    int c = 16 * ct + lr;
                    float sv = sacc[mt2][ct][r];
                    if (c < NT) {
                        if (rv) sv += bf2f(biash[R * NT + c]) + maskb[R * NT + c];
                    } else {
                        sv = -1e30f;
                    }
                    vals[ct] = sv;
                }
                float m = fmaxf(fmaxf(vals[0], vals[1]), fmaxf(vals[2], vals[3]));
                m = fmaxf(m, __shfl_xor(m, 1));
                m = fmaxf(m, __shfl_xor(m, 2));
                m = fmaxf(m, __shfl_xor(m, 4));
                m = fmaxf(m, __shfl_xor(m, 8));
                float sum = 0.f;
#pragma unroll
                for (int ct = 0; ct < 4; ++ct) {
                    float e = exp2f((vals[ct] - m) * LOG2E);
                    vals[ct] = e;
                    sum += e;
                }
                sum += __shfl_xor(sum, 1);
                sum += __shfl_xor(sum, 2);
                sum += __shfl_xor(sum, 4);
                sum += __shfl_xor(sum, 8);
                float inv = 1.0f / sum;
#pragma unroll
                for (int ct = 0; ct < 4; ++ct)
                    qh[R * QK_STRIDE + 16 * ct + lr] = f2bf(vals[ct] * inv);
            }
        }

        // ---- P @ V ----
        f32x4 oacc[2][2];
#pragma unroll
        for (int mt2 = 0; mt2 < 2; ++mt2)
#pragma unroll
            for (int nt = 0; nt < 2; ++nt)
                oacc[mt2][nt] = f32x4{0.f, 0.f, 0.f, 0.f};

#pragma unroll
        for (int mt2 = 0; mt2 < 2; ++mt2) {
            bf16x8 pa[2];
            pa[0] = *reinterpret_cast<const bf16x8*>(&qh[(16 * (mt0 + mt2) + lr) * QK_STRIDE + lg * 8]);
            pa[1] = *reinterpret_cast<const bf16x8*>(&qh[(16 * (mt0 + mt2) + lr) * QK_STRIDE + 32 + lg * 8]);
#pragma unroll
            for (int nt = 0; nt < 2; ++nt) {
                int dl = 16 * nt + lr;
#pragma unroll
                for (int ks = 0; ks < 2; ++ks) {
                    bf16x8 vb = *reinterpret_cast<const bf16x8*>(
                        &vT[h * 2048 + dl * 64 + ((ks * 32 + lg * 8) ^ ((dl & 7) << 3))]);
                    oacc[mt2][nt] = __builtin_amdgcn_mfma_f32_16x16x32_bf16(pa[ks], vb, oacc[mt2][nt], 0, 0, 0);
                }
            }
        }
        __syncthreads();   // all PV reads of vT done; vT region becomes o

        short* o = vT;     // [64][128] swizzled
#pragma unroll
        for (int mt2 = 0; mt2 < 2; ++mt2)
#pragma unroll
            for (int nt = 0; nt < 2; ++nt)
#pragma unroll
                for (int r = 0; r < 4; ++r) {
                    int row = 16 * (mt0 + mt2) + 4 * lg + r;
                    int col = 32 * h + 16 * nt + lr;
                    o[swz128(row, col)] = f2bf(oacc[mt2][nt][r]);
                }
    }
    __syncthreads();

    // ---- phase 4: proj. wave -> rows 16*wr..+16, col tiles n0..n0+3 ----
    {
        const short* o = vT;
        bf16x8 ao[4];
#pragma unroll
        for (int kt = 0; kt < 4; ++kt)
            ao[kt] = *reinterpret_cast<const bf16x8*>(&o[swz128(16 * wr + lr, kt * 32 + lg * 8)]);
        int n0 = wh * 4;
#pragma unroll
        for (int i = 0; i < 4; ++i) {
            int nt = n0 + i;
            f32x4 acc = {0.f, 0.f, 0.f, 0.f};
#pragma unroll
            for (int kt = 0; kt < 4; ++kt) {
                bf16x8 bb = *reinterpret_cast<const bf16x8*>(&projwT[(nt * 16 + lr) * 128 + kt * 32 + lg * 8]);
                acc = __builtin_amdgcn_mfma_f32_16x16x32_bf16(ao[kt], bb, acc, 0, 0, 0);
            }
            int col = nt * 16 + lr;
            float pb = proj_b[col];
#pragma unroll
            for (int r = 0; r < 4; ++r) {
                int row = 16 * wr + 4 * lg + r;
                if (row < NT)
                    out[((long)b * NT + row) * CD + col] = acc[r] + pb;
            }
        }
    }
}

extern "C" void kernel_launch(void* const* d_in, const int* in_sizes, int n_in,
                              void* d_out, int out_size, void* d_ws, size_t ws_size,
                              hipStream_t stream) {
    const float* x      = (const float*)d_in[0];
    const float* mask   = (const float*)d_in[1];
    const float* qkv_w  = (const float*)d_in[2];
    const float* qkv_b  = (const float*)d_in[3];
    const float* rbt    = (const float*)d_in[4];
    const float* proj_w = (const float*)d_in[5];
    const float* proj_b = (const float*)d_in[6];
    const int*   ridx   = (const int*)d_in[7];
    float* out = (float*)d_out;

    char* ws = (char*)d_ws;
    short* qkvwT  = (short*)(ws + WS_QKVWT);
    short* projwT = (short*)(ws + WS_PROJWT);
    unsigned short* biasBf = (unsigned short*)(ws + WS_BIAS);

    prep_kernel<<<192, 256, 0, stream>>>(qkv_w, proj_w, rbt, ridx, qkvwT, projwT, biasBf);
    winattn_kernel<<<NB, 512, 0, stream>>>(x, mask, qkv_b, proj_b, qkvwT, projwT, biasBf, out);
}